// Round 1
// baseline (529.387 us; speedup 1.0000x reference)
//
#include <hip/hip_runtime.h>
#include <stdint.h>

// Problem constants
#define Bsz 1024
#define Tn  20
#define Hn  768
#define G4n 3072   // 4*H

// Workspace layout (floats):
//  [0..31]    Sh[t]   : sum of h after step t (t=0..19), atomically accumulated
//  [32..63]   Sev[t]  : sum of batch_event[:,t,:]
//  [64..]     rowsum[20][3072]
//  [+61440]   biassum[20][3072] = b_ih + b_hh
//  [+61440]   c state [1024][768]
#define WS_SH   0
#define WS_SEV  32
#define WS_RS   64
#define WS_BS   (64 + Tn*G4n)
#define WS_C    (64 + 2*Tn*G4n)

typedef float  floatx4 __attribute__((ext_vector_type(4)));
typedef short  bfrag8  __attribute__((ext_vector_type(8)));

__device__ __forceinline__ float wave_reduce(float v){
#pragma unroll
    for (int o = 32; o > 0; o >>= 1) v += __shfl_down(v, o, 64);
    return v;
}
__device__ __forceinline__ float sigf(float x){ return 1.0f/(1.0f+__expf(-x)); }
__device__ __forceinline__ float tanhfast(float x){ return 2.0f/(1.0f+__expf(-2.0f*x)) - 1.0f; }
__device__ __forceinline__ unsigned short f2bf(float f){
    uint32_t u = __float_as_uint(f);
    return (unsigned short)((u + 0x7fffu + ((u>>16)&1u)) >> 16);
}
__device__ __forceinline__ float bf2f(unsigned short h){ return __uint_as_float(((uint32_t)h)<<16); }

// ---------------- K0: zero scalar slots ----------------
__global__ void k_init(float* __restrict__ ws){
    if (threadIdx.x < 64) ws[threadIdx.x] = 0.0f;
}

// ---------------- K1: rowsums, bias sums, per-step event sums ----------------
// grid: 14592 (rowsum, wave/row) + 240 (biassum) + 1216 (Sev) = 16048 blocks x 256
__global__ __launch_bounds__(256) void k_pre(
    const float* __restrict__ ev, const float* __restrict__ whh,
    const float* __restrict__ bih, const float* __restrict__ bhh,
    float* __restrict__ ws)
{
    __shared__ float red[4];
    int blk = blockIdx.x, tid = threadIdx.x;
    float* Sev     = ws + WS_SEV;
    float* rowsum  = ws + WS_RS;
    float* biassum = ws + WS_BS;

    if (blk < 14592) {                       // rowsum: rows for t=1..19 (58368 rows)
        int r    = blk*4 + (tid>>6);
        int lane = tid & 63;
        int t    = 1 + r/G4n;
        int j    = r - (t-1)*G4n;
        const float* base = whh + (size_t)t*G4n*Hn + (size_t)j*Hn;
        float s = 0.f;
#pragma unroll
        for (int i = 0; i < 3; ++i) {
            float4 v = *(const float4*)(base + (size_t)(lane + 64*i)*4);
            s += v.x + v.y + v.z + v.w;
        }
        s = wave_reduce(s);
        if (lane == 0) rowsum[t*G4n + j] = s;
    } else if (blk < 14832) {                // biassum
        int idx = (blk - 14592)*256 + tid;
        if (idx < Tn*G4n) biassum[idx] = bih[idx] + bhh[idx];
    } else {                                 // Sev[t], t=1..19, 64 blocks per t
        int sb = blk - 14832;
        int t  = 1 + (sb >> 6);
        int b0 = (sb & 63) * 16;
        float s = 0.f;
        for (int bb = 0; bb < 16; ++bb) {
            const float* base = ev + (size_t)(b0+bb)*(Tn*Hn) + (size_t)t*Hn;
            s += base[tid] + base[tid+256] + base[tid+512];
        }
        s = wave_reduce(s);
        if ((tid & 63) == 0) red[tid>>6] = s;
        __syncthreads();
        if (tid == 0) atomicAdd(&Sev[t], red[0]+red[1]+red[2]+red[3]);
    }
}

// ---------------- K2: t=0 gates GEMM (bf16x3 MFMA) + c0/h0 epilogue ----------------
// grid: 16 b-tiles x 48 k-tiles = 768 blocks x 256 threads.
// Block tile: 64 b  x  16 k_out  x  4 gates (64 whh rows). K-chunks of 32.
__global__ __launch_bounds__(256) void k_gemm0(
    const float* __restrict__ price, const float* __restrict__ ev,
    const float* __restrict__ wih,   const float* __restrict__ whh,
    const float* __restrict__ bih,   const float* __restrict__ bhh,
    float* __restrict__ ws)
{
    __shared__ unsigned short Ah[64*56], Al[64*56], Bh[64*56], Bl[64*56];
    __shared__ float redk[4];

    float* Sh   = ws + WS_SH;
    float* cbuf = ws + WS_C;

    int tid = threadIdx.x;
    int bt = blockIdx.x / 48, kt = blockIdx.x % 48;
    int b0 = bt*64, k0 = kt*16;
    int w = tid >> 6, lane = tid & 63;
    int q = lane >> 4, col = lane & 15;

    // staging assignment: thread stages 8 contraction elems of one A row and one B row
    int srow = tid >> 2;            // 0..63
    int kkoff = (tid & 3) * 8;      // 0,8,16,24
    int g_s = srow >> 4, rr = srow & 15;
    const float* aRow = ev  + (size_t)(b0 + srow)*(Tn*Hn);          // [b][t=0][kk]
    const float* bRow = whh + (size_t)(g_s*Hn + k0 + rr)*Hn;        // W_hh[0] row j

    floatx4 acc[4];
#pragma unroll
    for (int g = 0; g < 4; ++g) acc[g] = (floatx4){0.f,0.f,0.f,0.f};

    for (int kk0 = 0; kk0 < Hn; kk0 += 32) {
        {   // stage A
            const float* p = aRow + kk0 + kkoff;
            float4 v0 = *(const float4*)p;
            float4 v1 = *(const float4*)(p+4);
            float f[8] = {v0.x,v0.y,v0.z,v0.w,v1.x,v1.y,v1.z,v1.w};
            bfrag8 hv, lv;
#pragma unroll
            for (int i = 0; i < 8; ++i) {
                unsigned short hb = f2bf(f[i]);
                float hf = bf2f(hb);
                hv[i] = (short)hb;
                lv[i] = (short)f2bf(f[i] - hf);
            }
            *(bfrag8*)&Ah[srow*56 + kkoff] = hv;
            *(bfrag8*)&Al[srow*56 + kkoff] = lv;
            // stage B
            const float* pb = bRow + kk0 + kkoff;
            float4 u0 = *(const float4*)pb;
            float4 u1 = *(const float4*)(pb+4);
            float fb[8] = {u0.x,u0.y,u0.z,u0.w,u1.x,u1.y,u1.z,u1.w};
#pragma unroll
            for (int i = 0; i < 8; ++i) {
                unsigned short hb = f2bf(fb[i]);
                float hf = bf2f(hb);
                hv[i] = (short)hb;
                lv[i] = (short)f2bf(fb[i] - hf);
            }
            *(bfrag8*)&Bh[srow*56 + kkoff] = hv;
            *(bfrag8*)&Bl[srow*56 + kkoff] = lv;
        }
        __syncthreads();

        bfrag8 ah = *(const bfrag8*)&Ah[(w*16 + col)*56 + q*8];
        bfrag8 al = *(const bfrag8*)&Al[(w*16 + col)*56 + q*8];
#pragma unroll
        for (int g = 0; g < 4; ++g) {
            bfrag8 bh = *(const bfrag8*)&Bh[(g*16 + col)*56 + q*8];
            bfrag8 bl = *(const bfrag8*)&Bl[(g*16 + col)*56 + q*8];
            acc[g] = __builtin_amdgcn_mfma_f32_16x16x32_bf16(ah, bh, acc[g], 0,0,0);
            acc[g] = __builtin_amdgcn_mfma_f32_16x16x32_bf16(ah, bl, acc[g], 0,0,0);
            acc[g] = __builtin_amdgcn_mfma_f32_16x16x32_bf16(al, bh, acc[g], 0,0,0);
        }
        __syncthreads();
    }

    // Epilogue: lane holds D[row=q*4+r][col] for its wave's 16-b strip
    float hsum = 0.f;
#pragma unroll
    for (int r = 0; r < 4; ++r) {
        int b = b0 + w*16 + q*4 + r;
        float4 xv = *(const float4*)(price + (size_t)b*(Tn*4));   // x at t=0
        float gates[4];
#pragma unroll
        for (int g = 0; g < 4; ++g) {
            int j = g*Hn + k0 + col;
            float4 wv = *(const float4*)(wih + (size_t)j*4);      // W_ih[0][j][:]
            gates[g] = acc[g][r] + xv.x*wv.x + xv.y*wv.y + xv.z*wv.z + xv.w*wv.w
                     + bih[j] + bhh[j];
        }
        float c0 = sigf(gates[0]) * tanhfast(gates[2]);           // c=0 initially
        float h0 = sigf(gates[3]) * tanhfast(c0);
        cbuf[(size_t)b*Hn + k0 + col] = c0;
        hsum += h0;
    }
    hsum = wave_reduce(hsum);
    if (lane == 0) redk[w] = hsum;
    __syncthreads();
    if (tid == 0) atomicAdd(&Sh[0], redk[0]+redk[1]+redk[2]+redk[3]);
}

// ---------------- K3: one recurrence step (t = 1..19) ----------------
// grid: 256 blocks x 768 threads. k = tid, block handles b = blockIdx + 256*e.
__global__ __launch_bounds__(768) void k_step(
    const float* __restrict__ price, const float* __restrict__ wih,
    const float* __restrict__ fcw,   const float* __restrict__ fcb,
    float* __restrict__ ws, float* __restrict__ out, int t, int writeOut)
{
    __shared__ float red[12];
    float* Sh  = ws + WS_SH;
    float* Sev = ws + WS_SEV;
    const float* rs_t = ws + WS_RS + t*G4n;
    const float* bs_t = ws + WS_BS + t*G4n;
    float* cbuf = ws + WS_C;

    float hx = Sev[t] + Sh[t-1];
    int k = threadIdx.x;
    const float* wih_t = wih + (size_t)t*G4n*4;

    // hoisted per-k gate coefficients (shared across the 4 b's)
    float4 wv[4]; float cb[4];
#pragma unroll
    for (int g = 0; g < 4; ++g) {
        int j = g*Hn + k;
        wv[g] = *(const float4*)(wih_t + (size_t)j*4);
        cb[g] = bs_t[j] + hx*rs_t[j];
    }
    float fcwk = writeOut ? fcw[k] : 0.f;
    float fcb0 = writeOut ? fcb[0] : 0.f;

    float hsum = 0.f;
#pragma unroll
    for (int e = 0; e < 4; ++e) {
        int b = blockIdx.x + 256*e;
        float4 xv = *(const float4*)(price + (size_t)b*(Tn*4) + (size_t)t*4);
        float gi = xv.x*wv[0].x + xv.y*wv[0].y + xv.z*wv[0].z + xv.w*wv[0].w + cb[0];
        float gf = xv.x*wv[1].x + xv.y*wv[1].y + xv.z*wv[1].z + xv.w*wv[1].w + cb[1];
        float gg = xv.x*wv[2].x + xv.y*wv[2].y + xv.z*wv[2].z + xv.w*wv[2].w + cb[2];
        float go = xv.x*wv[3].x + xv.y*wv[3].y + xv.z*wv[3].z + xv.w*wv[3].w + cb[3];
        size_t idx = (size_t)b*Hn + k;
        float c  = cbuf[idx];
        float cn = sigf(gf)*c + sigf(gi)*tanhfast(gg);
        cbuf[idx] = cn;
        float h = sigf(go)*tanhfast(cn);
        hsum += h;

        if (writeOut) {   // t==19: fuse out[b] = h19[b,:] . fc_w + fc_b
            float v = wave_reduce(h * fcwk);
            int lane = threadIdx.x & 63, wid = threadIdx.x >> 6;
            __syncthreads();
            if (lane == 0) red[wid] = v;
            __syncthreads();
            if (threadIdx.x == 0) {
                float tot = 0.f;
                for (int i = 0; i < 12; ++i) tot += red[i];
                out[b] = tot + fcb0;
            }
        }
    }

    if (!writeOut) {      // accumulate Sh[t] for next step
        float v = wave_reduce(hsum);
        int lane = threadIdx.x & 63, wid = threadIdx.x >> 6;
        if (lane == 0) red[wid] = v;
        __syncthreads();
        if (threadIdx.x == 0) {
            float tot = 0.f;
            for (int i = 0; i < 12; ++i) tot += red[i];
            atomicAdd(&Sh[t], tot);
        }
    }
}

extern "C" void kernel_launch(void* const* d_in, const int* in_sizes, int n_in,
                              void* d_out, int out_size, void* d_ws, size_t ws_size,
                              hipStream_t stream)
{
    const float* price = (const float*)d_in[0];
    const float* ev    = (const float*)d_in[1];
    const float* wih   = (const float*)d_in[2];
    const float* whh   = (const float*)d_in[3];
    const float* bih   = (const float*)d_in[4];
    const float* bhh   = (const float*)d_in[5];
    const float* fcw   = (const float*)d_in[6];
    const float* fcb   = (const float*)d_in[7];
    float* out = (float*)d_out;
    float* ws  = (float*)d_ws;

    k_init<<<1, 64, 0, stream>>>(ws);
    k_pre<<<16048, 256, 0, stream>>>(ev, whh, bih, bhh, ws);
    k_gemm0<<<768, 256, 0, stream>>>(price, ev, wih, whh, bih, bhh, ws);
    for (int t = 1; t < Tn; ++t)
        k_step<<<256, 768, 0, stream>>>(price, wih, fcw, fcb, ws, out, t, (t == Tn-1) ? 1 : 0);
}